// Round 1
// baseline (52.414 us; speedup 1.0000x reference)
//
#include <hip/hip_runtime.h>

#define NB    256
#define QK    80000      // 1000 * 80
#define QK4   20000
#define K_TOP 300
#define NCLS  80
#define NCAND 2048
#define NBUCK 4096

__device__ __forceinline__ unsigned int order_f32(float f) {
    unsigned int u = __float_as_uint(f);
    return u ^ ((u >> 31) ? 0xFFFFFFFFu : 0x80000000u);
}
__device__ __forceinline__ float unorder_f32(unsigned int u) {
    unsigned int v = (u & 0x80000000u) ? (u ^ 0x80000000u) : ~u;
    return __uint_as_float(v);
}

__global__ __launch_bounds__(1024) void detr_post_kernel(
    const float* __restrict__ logits,
    const float* __restrict__ boxes,
    const int*   __restrict__ osz,
    float*       __restrict__ out)
{
    // cand (u64[2048], 16KB) aliases hist (u32[4096], 16KB): hist is dead
    // once the threshold bucket is found.
    __shared__ unsigned long long buf[NCAND];
    unsigned int*       hist = (unsigned int*)buf;
    unsigned long long* cand = buf;
    __shared__ unsigned int csum[1024];
    __shared__ unsigned int csum2[64];
    __shared__ int s_B;
    __shared__ int s_cnt;

    const int b = blockIdx.x;
    const int t = threadIdx.x;
    const float4* L4 = (const float4*)(logits + (size_t)b * QK);

    for (int i = t; i < NBUCK; i += 1024) hist[i] = 0;
    if (t == 0) s_cnt = 0;
    __syncthreads();

    // ---- pass 1: 12-bit histogram of ordered float bits ----
    for (int i = t; i < QK4; i += 1024) {
        float4 v = L4[i];
        atomicAdd(&hist[order_f32(v.x) >> 20], 1u);
        atomicAdd(&hist[order_f32(v.y) >> 20], 1u);
        atomicAdd(&hist[order_f32(v.z) >> 20], 1u);
        atomicAdd(&hist[order_f32(v.w) >> 20], 1u);
    }
    __syncthreads();

    // ---- hierarchical suffix scan from the top bucket to find bucket B:
    //      smallest B with count(bucket >= B) >= K_TOP ----
    csum[t] = hist[4*t] + hist[4*t+1] + hist[4*t+2] + hist[4*t+3];
    __syncthreads();
    if (t < 64) {
        unsigned int s = 0;
        for (int u = 0; u < 16; ++u) s += csum[16*t + u];
        csum2[t] = s;
    }
    __syncthreads();
    if (t == 0) {
        int total = 0;
        int S = 0, C = 0, B = 0;
        for (int s = 63; s >= 0; --s) {
            int c = (int)csum2[s];
            if (total + c >= K_TOP) { S = s; break; }
            total += c;
        }
        for (int c = S*16 + 15; c >= S*16; --c) {
            int cc = (int)csum[c];
            if (total + cc >= K_TOP) { C = c; break; }
            total += cc;
        }
        for (int bk = C*4 + 3; bk >= C*4; --bk) {
            int hh = (int)hist[bk];
            if (total + hh >= K_TOP) { B = bk; break; }
            total += hh;
        }
        s_B = B;
    }
    __syncthreads();           // after this, hist is dead -> reuse as cand
    const unsigned int B = (unsigned int)s_B;

    // ---- pass 2: collect candidates (bucket >= B) as 64-bit sort keys ----
    for (int i = t; i < QK4; i += 1024) {
        float4 v = L4[i];
        const int base = i * 4;
        float vv[4] = {v.x, v.y, v.z, v.w};
        #pragma unroll
        for (int j = 0; j < 4; ++j) {
            unsigned int o = order_f32(vv[j]);
            if ((o >> 20) >= B) {
                int pos = atomicAdd(&s_cnt, 1);
                if (pos < NCAND)
                    cand[pos] = ((unsigned long long)o << 32) |
                                (unsigned long long)(0xFFFFFFFFu - (unsigned int)(base + j));
            }
        }
    }
    __syncthreads();
    int cnt = s_cnt; if (cnt > NCAND) cnt = NCAND;
    for (int i = t; i < NCAND; i += 1024)
        if (i >= cnt) cand[i] = 0ull;
    __syncthreads();

    // ---- bitonic sort, descending, 2048 u64 keys, 1024 threads ----
    for (int k = 2; k <= NCAND; k <<= 1) {
        for (int j = k >> 1; j > 0; j >>= 1) {
            #pragma unroll
            for (int w = 0; w < 2; ++w) {
                int i = t + w * 1024;
                int ixj = i ^ j;
                if (ixj > i) {
                    unsigned long long a = cand[i], c = cand[ixj];
                    bool desc = ((i & k) == 0);
                    if (desc ? (a < c) : (a > c)) { cand[i] = c; cand[ixj] = a; }
                }
            }
            __syncthreads();
        }
    }

    // ---- epilogue: decode top-300, gather boxes, scale, write ----
    const float sx = (float)osz[1];   // scale = [W, H, W, H]
    const float sy = (float)osz[0];
    const float4* BX = (const float4*)(boxes + (size_t)b * 4000);
    for (int i = t; i < K_TOP; i += 1024) {
        unsigned long long key = cand[i];
        unsigned int o   = (unsigned int)(key >> 32);
        unsigned int idx = ~((unsigned int)key);
        float logit = unorder_f32(o);
        float score = 1.0f / (1.0f + expf(-logit));
        int label = (int)(idx % NCLS);
        int q     = (int)(idx / NCLS);
        float4 bx = BX[q];
        float* po = out + ((size_t)b * K_TOP + i) * 6;
        po[0] = (float)label;
        po[1] = score;
        po[2] = (bx.x - 0.5f * bx.z) * sx;
        po[3] = (bx.y - 0.5f * bx.w) * sy;
        po[4] = bx.z * sx;
        po[5] = bx.w * sy;
    }
}

extern "C" void kernel_launch(void* const* d_in, const int* in_sizes, int n_in,
                              void* d_out, int out_size, void* d_ws, size_t ws_size,
                              hipStream_t stream) {
    const float* logits = (const float*)d_in[0];
    const float* boxes  = (const float*)d_in[1];
    const int*   osz    = (const int*)d_in[2];
    float* out = (float*)d_out;
    detr_post_kernel<<<dim3(NB), dim3(1024), 0, stream>>>(logits, boxes, osz, out);
}

// Round 2
// 46.960 us; speedup vs baseline: 1.1161x; 1.1161x over previous
//
#include <hip/hip_runtime.h>

#define QK4   20000      // 80000 floats / 4 per float4, per batch
#define K_TOP 300
#define NCLS  80
#define NCAND 2048
#define NBUCK 4096

__device__ __forceinline__ unsigned int order_f32(float f) {
    unsigned int u = __float_as_uint(f);
    return u ^ ((u >> 31) ? 0xFFFFFFFFu : 0x80000000u);
}
__device__ __forceinline__ float unorder_f32(unsigned int u) {
    unsigned int v = (u & 0x80000000u) ? (u ^ 0x80000000u) : ~u;
    return __uint_as_float(v);
}

#define HIST4(v)                                   \
    do {                                           \
        atomicAdd(&hist[order_f32((v).x) >> 20], 1u); \
        atomicAdd(&hist[order_f32((v).y) >> 20], 1u); \
        atomicAdd(&hist[order_f32((v).z) >> 20], 1u); \
        atomicAdd(&hist[order_f32((v).w) >> 20], 1u); \
    } while (0)

__device__ __forceinline__ void collect1(float v, int idx, unsigned int B,
                                         unsigned long long* cand, int* pcnt) {
    unsigned int o = order_f32(v);
    if ((o >> 20) >= B) {
        int pos = atomicAdd(pcnt, 1);
        if (pos < NCAND)
            cand[pos] = ((unsigned long long)o << 32) |
                        (unsigned long long)(0xFFFFFFFFu - (unsigned int)idx);
    }
}

#define COLL4(v, base)                                  \
    do {                                                \
        collect1((v).x, (base) + 0, B, cand, &s_cnt);   \
        collect1((v).y, (base) + 1, B, cand, &s_cnt);   \
        collect1((v).z, (base) + 2, B, cand, &s_cnt);   \
        collect1((v).w, (base) + 3, B, cand, &s_cnt);   \
    } while (0)

__device__ __forceinline__ void write_row(float* __restrict__ out, int b, int rank,
                                          unsigned long long key,
                                          const float4* __restrict__ BX,
                                          float sx, float sy) {
    unsigned int o   = (unsigned int)(key >> 32);
    unsigned int idx = ~((unsigned int)key);
    float logit = unorder_f32(o);
    float score = 1.0f / (1.0f + expf(-logit));
    int label = (int)(idx % NCLS);
    int q     = (int)(idx / NCLS);
    float4 bx = BX[q];
    float* po = out + ((size_t)b * K_TOP + rank) * 6;
    po[0] = (float)label;
    po[1] = score;
    po[2] = (bx.x - 0.5f * bx.z) * sx;
    po[3] = (bx.y - 0.5f * bx.w) * sy;
    po[4] = bx.z * sx;
    po[5] = bx.w * sy;
}

__global__ __launch_bounds__(1024) void detr_post_kernel(
    const float* __restrict__ logits,
    const float* __restrict__ boxes,
    const int*   __restrict__ osz,
    float*       __restrict__ out)
{
    // cand (u64[2048], 16KB) aliases hist (u32[4096], 16KB): hist is dead
    // once the threshold bucket is found.
    __shared__ unsigned long long buf[NCAND];
    unsigned int*       hist = (unsigned int*)buf;
    unsigned long long* cand = buf;
    __shared__ unsigned int csum[1024];
    __shared__ unsigned int csum2[64];
    __shared__ int s_B;
    __shared__ int s_cnt;

    const int b = blockIdx.x;
    const int t = threadIdx.x;
    const float4* L4 = (const float4*)(logits + (size_t)b * (QK4 * 4));

    for (int i = t; i < NBUCK; i += 1024) hist[i] = 0;
    if (t == 0) s_cnt = 0;
    __syncthreads();

    // ---- pass 1: 12-bit histogram; 4 loads in flight ahead of atomics ----
    {
        int i = t;
        #pragma unroll
        for (int c = 0; c < 4; ++c, i += 4096) {
            float4 a0 = L4[i];
            float4 a1 = L4[i + 1024];
            float4 a2 = L4[i + 2048];
            float4 a3 = L4[i + 3072];
            HIST4(a0); HIST4(a1); HIST4(a2); HIST4(a3);
        }
        // i == t + 16384; rounds 16..18 always valid, round 19 for t < 544
        float4 a0 = L4[i];
        float4 a1 = L4[i + 1024];
        float4 a2 = L4[i + 2048];
        float4 a3;
        if (t < 544) a3 = L4[19456 + t];
        HIST4(a0); HIST4(a1); HIST4(a2);
        if (t < 544) HIST4(a3);
    }
    __syncthreads();

    // ---- hierarchical suffix scan: smallest B with count(>= B) >= K_TOP ----
    csum[t] = hist[4*t] + hist[4*t+1] + hist[4*t+2] + hist[4*t+3];
    __syncthreads();
    if (t < 64) {
        unsigned int s = 0;
        for (int u = 0; u < 16; ++u) s += csum[16*t + u];
        csum2[t] = s;
    }
    __syncthreads();
    if (t == 0) {
        int total = 0;
        int S = 0, C = 0, B = 0;
        for (int s = 63; s >= 0; --s) {
            int c = (int)csum2[s];
            if (total + c >= K_TOP) { S = s; break; }
            total += c;
        }
        for (int c = S*16 + 15; c >= S*16; --c) {
            int cc = (int)csum[c];
            if (total + cc >= K_TOP) { C = c; break; }
            total += cc;
        }
        for (int bk = C*4 + 3; bk >= C*4; --bk) {
            int hh = (int)hist[bk];
            if (total + hh >= K_TOP) { B = bk; break; }
            total += hh;
        }
        s_B = B;
    }
    __syncthreads();           // hist is dead from here -> buf reused as cand
    const unsigned int B = (unsigned int)s_B;

    // ---- pass 2 (L2/L3-resident): collect candidates, 4 loads in flight ----
    {
        int i = t;
        #pragma unroll
        for (int c = 0; c < 4; ++c, i += 4096) {
            float4 a0 = L4[i];
            float4 a1 = L4[i + 1024];
            float4 a2 = L4[i + 2048];
            float4 a3 = L4[i + 3072];
            COLL4(a0, 4*i); COLL4(a1, 4*(i+1024));
            COLL4(a2, 4*(i+2048)); COLL4(a3, 4*(i+3072));
        }
        float4 a0 = L4[i];
        float4 a1 = L4[i + 1024];
        float4 a2 = L4[i + 2048];
        float4 a3;
        if (t < 544) a3 = L4[19456 + t];
        COLL4(a0, 4*i); COLL4(a1, 4*(i+1024)); COLL4(a2, 4*(i+2048));
        if (t < 544) COLL4(a3, 4*(19456 + t));
    }
    __syncthreads();
    const int cnt = (s_cnt < NCAND) ? s_cnt : NCAND;

    // ---- rank by counting (keys unique -> ranks are a perfect permutation).
    //      Broadcast LDS reads, zero barriers. ----
    const float sx = (float)osz[1];   // scale = [W, H, W, H]
    const float sy = (float)osz[0];
    const float4* BX = (const float4*)(boxes + (size_t)b * 4000);

    if (t < cnt) {
        unsigned long long k0 = cand[t];
        unsigned long long k1 = (t + 1024 < cnt) ? cand[t + 1024] : 0xFFFFFFFFFFFFFFFFull;
        int r0 = 0, r1 = 0;
        for (int k = 0; k < cnt; ++k) {
            unsigned long long c = cand[k];
            r0 += (c > k0) ? 1 : 0;
            r1 += (c > k1) ? 1 : 0;
        }
        if (r0 < K_TOP)
            write_row(out, b, r0, k0, BX, sx, sy);
        if (t + 1024 < cnt && r1 < K_TOP)
            write_row(out, b, r1, k1, BX, sx, sy);
    }
}

extern "C" void kernel_launch(void* const* d_in, const int* in_sizes, int n_in,
                              void* d_out, int out_size, void* d_ws, size_t ws_size,
                              hipStream_t stream) {
    const float* logits = (const float*)d_in[0];
    const float* boxes  = (const float*)d_in[1];
    const int*   osz    = (const int*)d_in[2];
    float* out = (float*)d_out;
    detr_post_kernel<<<dim3(256), dim3(1024), 0, stream>>>(logits, boxes, osz, out);
}